// Round 8
// baseline (44.122 us; speedup 1.0000x reference)
//
#include <hip/hip_runtime.h>
#include <math.h>

#define NPTS 2048
#define QQ 8
#define LAT 64
#define LOG2E 1.4426950408889634f
#define SQRT_LOG2E 1.2011224087864498f
#define LN2 0.6931471805599453f

typedef float v2f __attribute__((ext_vector_type(2)));

// Feature buffer layout (per side): [3 feats][QQ][n]
//   feat 0: ca = a * cos(2*pi*phase)     where a = w * 2^(1/4) * sqrt(s)
//   feat 1: sa = a * sin(2*pi*phase)
//   feat 2: s2 = s*s
#define FSTRIDE (QQ * NPTS)

__device__ __forceinline__ float exp2_fast(float v) { return __builtin_amdgcn_exp2f(v); }
__device__ __forceinline__ float log2_fast(float v) { return __builtin_amdgcn_logf(v); }

__device__ __forceinline__ float softplus_f(float v) {
    return fmaxf(v, 0.f) + LN2 * log2_fast(1.f + exp2_fast(-fabsf(v) * LOG2E));
}

// One thread per (point, q). Block: 128 threads = 16 points x 8 q.
// Grid: 256 blocks (0..127 -> x, 128..255 -> y).
__global__ __launch_bounds__(128) void feat_kernel(
    const float* __restrict__ x, const float* __restrict__ y,
    const float* __restrict__ W1, const float* __restrict__ b1,
    const float* __restrict__ Ww, const float* __restrict__ bw,
    const float* __restrict__ Wf, const float* __restrict__ bf,
    const float* __restrict__ Ws, const float* __restrict__ bs,
    float* __restrict__ FX, float* __restrict__ FY)
{
    __shared__ float4 lw1[LAT];        // W1 row + b1, 1 KiB
    __shared__ float  hw[LAT][QQ][8];  // [l][q][head0..4, pad] = 16 KiB

    const int t = threadIdx.x;
    if (t < LAT) lw1[t] = make_float4(W1[t*3+0], W1[t*3+1], W1[t*3+2], b1[t]);
    #pragma unroll
    for (int j = 0; j < 4; ++j) { int e = t + j*128; hw[e&63][e>>6][0] = Ww[e]; }
    #pragma unroll
    for (int j = 0; j < 4; ++j) { int e = t + j*128; hw[e&63][e>>6][1] = Ws[e]; }
    #pragma unroll
    for (int j = 0; j < 12; ++j) {
        int e = t + j*128; int r = e>>6, l = e&63;
        int q = r/3, d = r - 3*q;
        hw[l][q][2+d] = Wf[e];
    }
    __syncthreads();

    const int side = blockIdx.x >> 7;                       // 0: x, 1: y
    const int i = ((blockIdx.x & 127) << 4) + (t & 15);     // point index
    const int q = t >> 4;
    const float* P = side ? y : x;
    float* F = side ? FY : FX;

    const float p0 = P[i*3+0], p1 = P[i*3+1], p2 = P[i*3+2];
    float w  = bw[q],     s  = bs[q];
    float f0 = bf[q*3+0], f1 = bf[q*3+1], f2 = bf[q*3+2];
    const float lam = 1.0507009873554805f, lamalf = 1.7580993408473766f;

    #pragma unroll
    for (int l = 0; l < LAT; ++l) {
        float4 wr = lw1[l];
        float v = fmaf(wr.x, p0, fmaf(wr.y, p1, fmaf(wr.z, p2, wr.w)));
        float e = exp2_fast(v * LOG2E);
        float h = v > 0.f ? lam * v : lamalf * (e - 1.f);
        float4 hv = *(const float4*)&hw[l][q][0];   // w, s, f0, f1
        float  h5 = hw[l][q][4];                    // f2
        w  = fmaf(hv.x, h, w);
        s  = fmaf(hv.y, h, s);
        f0 = fmaf(hv.z, h, f0);
        f1 = fmaf(hv.w, h, f1);
        f2 = fmaf(h5,   h, f2);
    }
    w  = softplus_f(w);
    s  = softplus_f(s);
    f0 = softplus_f(f0);
    f1 = softplus_f(f1);
    f2 = softplus_f(f2);
    float phase = f0*p0 + f1*p1 + f2*p2;
    float fr = phase - floorf(phase);
    float sn = __builtin_amdgcn_sinf(fr);
    float cs = __builtin_amdgcn_cosf(fr);
    float a  = w * 1.1892071150027210f * sqrtf(s);
    F[0*FSTRIDE + q*NPTS + i] = a * cs;
    F[1*FSTRIDE + q*NPTS + i] = a * sn;
    F[2*FSTRIDE + q*NPTS + i] = s * s;
}

// ===== DIAGNOSTIC ROUND: q-loop executed 4x (REPS), acc scaled by 1/4 at the
// end. Purpose: push pair above the 40us poison-fills so rocprof's top-5
// finally shows its VALUBusy/Occupancy/VGPR. (dur_R8 - dur_R7)/3 = pair cost.
#define REPS 4

// Tile: 32 (i, from x) x 64 (j, from y). 256 threads, 8 outputs each (4i x 2j).
__global__ __launch_bounds__(256, 8) void pair_kernel(
    const float* __restrict__ x, const float* __restrict__ y,
    const float* __restrict__ FX, const float* __restrict__ FY,
    float* __restrict__ K)
{
    __shared__ float lfi[3][QQ][32];   // 3 KiB
    __shared__ float lfj[3][QQ][64];   // 6 KiB
    __shared__ float lpi[3][32];       // 384 B (pre-scaled by sqrt(log2 e))
    __shared__ float lpj[3][64];       // 768 B

    const int t  = threadIdx.x;
    const int tx = t & 31;             // j-group: 2 cols each
    const int ty = t >> 5;             // i-group: 4 rows each
    const int i0 = blockIdx.y * 32, j0 = blockIdx.x * 64;

    #pragma unroll
    for (int k = 0; k < 3; ++k) {
        int idx = t + k * 256;             // 0..767
        int f = idx >> 8, rem = idx & 255, q = rem >> 5, ii = rem & 31;
        lfi[f][q][ii] = FX[f*FSTRIDE + q*NPTS + i0 + ii];
    }
    #pragma unroll
    for (int k = 0; k < 6; ++k) {
        int idx = t + k * 256;             // 0..1535
        int f = idx >> 9, q = (idx >> 6) & 7, jj = idx & 63;
        lfj[f][q][jj] = FY[f*FSTRIDE + q*NPTS + j0 + jj];
    }
    if (t < 96) {
        int d = t >> 5, ii = t & 31;
        lpi[d][ii] = x[(i0 + ii)*3 + d] * SQRT_LOG2E;
    }
    if (t < 192) {
        int d = t >> 6, jj = t & 63;
        lpj[d][jj] = y[(j0 + jj)*3 + d] * SQRT_LOG2E;
    }
    __syncthreads();

    v2f yj0 = *(const v2f*)&lpj[0][tx*2];
    v2f yj1 = *(const v2f*)&lpj[1][tx*2];
    v2f yj2 = *(const v2f*)&lpj[2][tx*2];
    float4 xi0 = *(const float4*)&lpi[0][ty*4];
    float4 xi1 = *(const float4*)&lpi[1][ty*4];
    float4 xi2 = *(const float4*)&lpi[2][ty*4];
    float xs0[4] = {xi0.x, xi0.y, xi0.z, xi0.w};
    float xs1[4] = {xi1.x, xi1.y, xi1.z, xi1.w};
    float xs2[4] = {xi2.x, xi2.y, xi2.z, xi2.w};

    v2f d2n[4];
    #pragma unroll
    for (int ii = 0; ii < 4; ++ii) {
        v2f dx = xs0[ii] - yj0;
        v2f dy = xs1[ii] - yj1;
        v2f dz = xs2[ii] - yj2;
        d2n[ii] = -(dx*dx + dy*dy + dz*dz);
    }

    v2f acc[4] = {};
    #pragma unroll 1
    for (int rep = 0; rep < REPS; ++rep) {
        #pragma unroll 1
        for (int q = 0; q < QQ; ++q) {
            float4 cai4 = *(const float4*)&lfi[0][q][ty*4];
            float4 sai4 = *(const float4*)&lfi[1][q][ty*4];
            float4 s2i4 = *(const float4*)&lfi[2][q][ty*4];
            v2f caj = *(const v2f*)&lfj[0][q][tx*2];
            v2f saj = *(const v2f*)&lfj[1][q][tx*2];
            v2f s2j = *(const v2f*)&lfj[2][q][tx*2];
            float cai[4] = {cai4.x, cai4.y, cai4.z, cai4.w};
            float sai[4] = {sai4.x, sai4.y, sai4.z, sai4.w};
            float s2i[4] = {s2i4.x, s2i4.y, s2i4.z, s2i4.w};
            #pragma unroll
            for (int ii = 0; ii < 4; ++ii) {
                v2f s2  = s2i[ii] + s2j;
                v2f inv = { __builtin_amdgcn_rcpf(s2.x), __builtin_amdgcn_rcpf(s2.y) };
                v2f tt  = d2n[ii] * inv;
                v2f e   = { exp2_fast(tt.x), exp2_fast(tt.y) };
                v2f ct  = cai[ii]*caj + sai[ii]*saj;
                acc[ii] += (inv * e) * ct;
            }
        }
    }

    #pragma unroll
    for (int ii = 0; ii < 4; ++ii) {
        int i = i0 + ty*4 + ii;
        float2 o = make_float2(acc[ii].x * (1.0f/REPS), acc[ii].y * (1.0f/REPS));
        *(float2*)&K[(size_t)i * NPTS + j0 + tx*2] = o;
    }
}

extern "C" void kernel_launch(void* const* d_in, const int* in_sizes, int n_in,
                              void* d_out, int out_size, void* d_ws, size_t ws_size,
                              hipStream_t stream) {
    const float* x  = (const float*)d_in[0];
    const float* y  = (const float*)d_in[1];
    const float* W1 = (const float*)d_in[2];
    const float* b1 = (const float*)d_in[3];
    const float* Ww = (const float*)d_in[4];
    const float* bw = (const float*)d_in[5];
    const float* Wf = (const float*)d_in[6];
    const float* bf = (const float*)d_in[7];
    const float* Ws = (const float*)d_in[8];
    const float* bs = (const float*)d_in[9];
    float* K = (float*)d_out;

    float* FX = (float*)d_ws;                      // 3*8*2048 floats = 192 KiB
    float* FY = FX + 3 * FSTRIDE;                  // another 192 KiB

    feat_kernel<<<256, 128, 0, stream>>>(x, y, W1, b1, Ww, bw, Wf, bf, Ws, bs, FX, FY);

    dim3 grid(NPTS/64, NPTS/32);
    pair_kernel<<<grid, 256, 0, stream>>>(x, y, FX, FY, K);
}

// Round 10
// 23.164 us; speedup vs baseline: 1.9048x; 1.9048x over previous
//
#include <hip/hip_runtime.h>
#include <math.h>

#define NPTS 2048
#define QQ 8
#define LAT 64
#define LOG2E 1.4426950408889634f
#define SQRT_LOG2E 1.2011224087864498f
#define LN2 0.6931471805599453f
#define FSTRIDE (QQ * NPTS)

typedef float v2f __attribute__((ext_vector_type(2)));

__device__ __forceinline__ float exp2_fast(float v) { return __builtin_amdgcn_exp2f(v); }
__device__ __forceinline__ float log2_fast(float v) { return __builtin_amdgcn_logf(v); }

__device__ __forceinline__ float softplus_f(float v) {
    return fmaxf(v, 0.f) + LN2 * log2_fast(1.f + exp2_fast(-fabsf(v) * LOG2E));
}

// feat v4: ONE POINT PER WAVE. 1024 blocks x 256 thr = 4096 waves (4/SIMD).
// Lane layout: q = lane>>3 (8 q's), c = lane&7 (l-chunk). Each lane
// accumulates head dot-products over l in {8*it + c}; 3x shfl_xor reduces
// over c. No LDS, no barriers; weights (10 KB) served from L1/L2.
__global__ __launch_bounds__(256) void feat_kernel(
    const float* __restrict__ x, const float* __restrict__ y,
    const float* __restrict__ W1, const float* __restrict__ b1,
    const float* __restrict__ Ww, const float* __restrict__ bw,
    const float* __restrict__ Wf, const float* __restrict__ bf,
    const float* __restrict__ Ws, const float* __restrict__ bs,
    float* __restrict__ FX, float* __restrict__ FY)
{
    const int t    = threadIdx.x;
    const int wv   = t >> 6;            // wave in block (0..3)
    const int lane = t & 63;
    const int c    = lane & 7;          // l-chunk
    const int q    = lane >> 3;         // mixture component
    const int bid  = blockIdx.x;
    const int side = bid >> 9;          // 0: x (bid 0..511), 1: y
    const int i    = (bid & 511) * 4 + wv;
    const float* P = side ? y : x;
    float* F = side ? FY : FX;

    const float p0 = P[i*3+0], p1 = P[i*3+1], p2 = P[i*3+2];  // wave-uniform
    const float lam = 1.0507009873554805f, lamalf = 1.7580993408473766f;

    float wa = 0.f, sa = 0.f, f0a = 0.f, f1a = 0.f, f2a = 0.f;
    #pragma unroll
    for (int it = 0; it < 8; ++it) {
        int l = it*8 + c;
        float v = fmaf(W1[l*3+0], p0, fmaf(W1[l*3+1], p1, fmaf(W1[l*3+2], p2, b1[l])));
        float e = exp2_fast(v * LOG2E);
        float h = v > 0.f ? lam * v : lamalf * (e - 1.f);
        wa  = fmaf(Ww[q*LAT + l],       h, wa);
        sa  = fmaf(Ws[q*LAT + l],       h, sa);
        f0a = fmaf(Wf[(q*3+0)*LAT + l], h, f0a);
        f1a = fmaf(Wf[(q*3+1)*LAT + l], h, f1a);
        f2a = fmaf(Wf[(q*3+2)*LAT + l], h, f2a);
    }
    // Reduce over c = lane bits 0..2 (q preserved).
    #pragma unroll
    for (int m = 1; m <= 4; m <<= 1) {
        wa  += __shfl_xor(wa,  m, 64);
        sa  += __shfl_xor(sa,  m, 64);
        f0a += __shfl_xor(f0a, m, 64);
        f1a += __shfl_xor(f1a, m, 64);
        f2a += __shfl_xor(f2a, m, 64);
    }
    float w  = softplus_f(wa  + bw[q]);
    float s  = softplus_f(sa  + bs[q]);
    float f0 = softplus_f(f0a + bf[q*3+0]);
    float f1 = softplus_f(f1a + bf[q*3+1]);
    float f2 = softplus_f(f2a + bf[q*3+2]);
    float phase = f0*p0 + f1*p1 + f2*p2;
    float fr = phase - floorf(phase);
    float sn = __builtin_amdgcn_sinf(fr);
    float cs = __builtin_amdgcn_cosf(fr);
    float a  = w * 1.1892071150027210f * sqrtf(s);
    if (c == 0) {
        F[0*FSTRIDE + q*NPTS + i] = a * cs;
        F[1*FSTRIDE + q*NPTS + i] = a * sn;
        F[2*FSTRIDE + q*NPTS + i] = s * s;
    }
}

// Pair: R7's verified kernel, unchanged. Tile 32(i) x 64(j), 256 thr,
// 8 outputs each (4i x 2j), 2048 blocks.
__global__ __launch_bounds__(256, 8) void pair_kernel(
    const float* __restrict__ x, const float* __restrict__ y,
    const float* __restrict__ FX, const float* __restrict__ FY,
    float* __restrict__ K)
{
    __shared__ float lfi[3][QQ][32];   // 3 KiB
    __shared__ float lfj[3][QQ][64];   // 6 KiB
    __shared__ float lpi[3][32];       // 384 B (pre-scaled by sqrt(log2 e))
    __shared__ float lpj[3][64];       // 768 B

    const int t  = threadIdx.x;
    const int tx = t & 31;             // j-group: 2 cols each
    const int ty = t >> 5;             // i-group: 4 rows each
    const int i0 = blockIdx.y * 32, j0 = blockIdx.x * 64;

    #pragma unroll
    for (int k = 0; k < 3; ++k) {
        int idx = t + k * 256;             // 0..767
        int f = idx >> 8, rem = idx & 255, q = rem >> 5, ii = rem & 31;
        lfi[f][q][ii] = FX[f*FSTRIDE + q*NPTS + i0 + ii];
    }
    #pragma unroll
    for (int k = 0; k < 6; ++k) {
        int idx = t + k * 256;             // 0..1535
        int f = idx >> 9, q = (idx >> 6) & 7, jj = idx & 63;
        lfj[f][q][jj] = FY[f*FSTRIDE + q*NPTS + j0 + jj];
    }
    if (t < 96) {
        int d = t >> 5, ii = t & 31;
        lpi[d][ii] = x[(i0 + ii)*3 + d] * SQRT_LOG2E;
    }
    if (t < 192) {
        int d = t >> 6, jj = t & 63;
        lpj[d][jj] = y[(j0 + jj)*3 + d] * SQRT_LOG2E;
    }
    __syncthreads();

    v2f yj0 = *(const v2f*)&lpj[0][tx*2];
    v2f yj1 = *(const v2f*)&lpj[1][tx*2];
    v2f yj2 = *(const v2f*)&lpj[2][tx*2];
    float4 xi0 = *(const float4*)&lpi[0][ty*4];
    float4 xi1 = *(const float4*)&lpi[1][ty*4];
    float4 xi2 = *(const float4*)&lpi[2][ty*4];
    float xs0[4] = {xi0.x, xi0.y, xi0.z, xi0.w};
    float xs1[4] = {xi1.x, xi1.y, xi1.z, xi1.w};
    float xs2[4] = {xi2.x, xi2.y, xi2.z, xi2.w};

    v2f d2n[4];
    #pragma unroll
    for (int ii = 0; ii < 4; ++ii) {
        v2f dx = xs0[ii] - yj0;
        v2f dy = xs1[ii] - yj1;
        v2f dz = xs2[ii] - yj2;
        d2n[ii] = -(dx*dx + dy*dy + dz*dz);
    }

    v2f acc[4] = {};
    #pragma unroll 1
    for (int q = 0; q < QQ; ++q) {
        float4 cai4 = *(const float4*)&lfi[0][q][ty*4];
        float4 sai4 = *(const float4*)&lfi[1][q][ty*4];
        float4 s2i4 = *(const float4*)&lfi[2][q][ty*4];
        v2f caj = *(const v2f*)&lfj[0][q][tx*2];
        v2f saj = *(const v2f*)&lfj[1][q][tx*2];
        v2f s2j = *(const v2f*)&lfj[2][q][tx*2];
        float cai[4] = {cai4.x, cai4.y, cai4.z, cai4.w};
        float sai[4] = {sai4.x, sai4.y, sai4.z, sai4.w};
        float s2i[4] = {s2i4.x, s2i4.y, s2i4.z, s2i4.w};
        #pragma unroll
        for (int ii = 0; ii < 4; ++ii) {
            v2f s2  = s2i[ii] + s2j;
            v2f inv = { __builtin_amdgcn_rcpf(s2.x), __builtin_amdgcn_rcpf(s2.y) };
            v2f tt  = d2n[ii] * inv;
            v2f e   = { exp2_fast(tt.x), exp2_fast(tt.y) };
            v2f ct  = cai[ii]*caj + sai[ii]*saj;
            acc[ii] += (inv * e) * ct;
        }
    }

    #pragma unroll
    for (int ii = 0; ii < 4; ++ii) {
        int i = i0 + ty*4 + ii;
        float2 o = make_float2(acc[ii].x, acc[ii].y);
        *(float2*)&K[(size_t)i * NPTS + j0 + tx*2] = o;
    }
}

extern "C" void kernel_launch(void* const* d_in, const int* in_sizes, int n_in,
                              void* d_out, int out_size, void* d_ws, size_t ws_size,
                              hipStream_t stream) {
    const float* x  = (const float*)d_in[0];
    const float* y  = (const float*)d_in[1];
    const float* W1 = (const float*)d_in[2];
    const float* b1 = (const float*)d_in[3];
    const float* Ww = (const float*)d_in[4];
    const float* bw = (const float*)d_in[5];
    const float* Wf = (const float*)d_in[6];
    const float* bf = (const float*)d_in[7];
    const float* Ws = (const float*)d_in[8];
    const float* bs = (const float*)d_in[9];
    float* K = (float*)d_out;

    float* FX = (float*)d_ws;                      // 3*8*2048 floats = 192 KiB
    float* FY = FX + 3 * FSTRIDE;                  // another 192 KiB

    feat_kernel<<<1024, 256, 0, stream>>>(x, y, W1, b1, Ww, bw, Wf, bf, Ws, bs, FX, FY);

    dim3 grid(NPTS/64, NPTS/32);
    pair_kernel<<<grid, 256, 0, stream>>>(x, y, FX, FY, K);
}